// Round 5
// baseline (286.339 us; speedup 1.0000x reference)
//
#include <hip/hip_runtime.h>
#include <math.h>

#define NEG_SLOPE 0.2f
#define LN_EPS 1e-5f

typedef __attribute__((ext_vector_type(8))) short bf16x8;
typedef __attribute__((ext_vector_type(4))) float f32x4;

// fp32 -> bf16 (RTNE)
static __device__ __forceinline__ unsigned short f2bf(float f) {
  unsigned u = __float_as_uint(f);
  u += 0x7fffu + ((u >> 16) & 1u);
  return (unsigned short)(u >> 16);
}
static __device__ __forceinline__ float bf2f(unsigned short b) {
  return __uint_as_float((unsigned)b << 16);
}
// pack two fp32 into bf16x2 (RTNE), elem0 in low half
static __device__ __forceinline__ unsigned pack_bf16(float a, float b) {
  unsigned ua = __float_as_uint(a);
  unsigned ub = __float_as_uint(b);
  ua += 0x7fffu + ((ua >> 16) & 1u);
  ub += 0x7fffu + ((ub >> 16) & 1u);
  return (ua >> 16) | (ub & 0xffff0000u);
}
static __device__ __forceinline__ float bf_lo(unsigned u) { return __uint_as_float(u << 16); }
static __device__ __forceinline__ float bf_hi(unsigned u) { return __uint_as_float(u & 0xffff0000u); }

// ---------------------------------------------------------------------------
// k_proj_count: MFMA projection (split-bf16: h = x_hi@W + x_lo@W) + fused
// degree-count role blocks + fused attention scalars via a 9th B col-tile:
//   wa[k][n] (n<8): n = head*2 + (src?0:1... n&1: 0=src,1=dst)
//   sc[row][n]   = (x@wa)[row][n]  ->  ssrc = sc[.][h*2], sdst = sc[.][h*2+1]
//  Proj blocks: 128 rows (4 waves x 2 row-tiles of 16). W staged once in LDS
//  in B-fragment order (32 KB bf16) + wa tile (4 KB).
//  mfma_f32_16x16x32_bf16 layouts (HW-verified, guide §3):
//    A: lane holds A[m=lane&15][k=(lane>>4)*8+j]   (j=0..7)
//    B: lane holds B[k=(lane>>4)*8+j][n=lane&15]
//    C/D: lane holds D[row=(lane>>4)*4+reg][col=lane&15]
// ---------------------------------------------------------------------------
__global__ __launch_bounds__(256) void k_proj_count(
    const float* __restrict__ x, const float* __restrict__ W,
    const float* __restrict__ a_src, const float* __restrict__ a_dst,
    unsigned* __restrict__ h, float* __restrict__ sc, int n_nodes,
    const int* __restrict__ e_dst, int* __restrict__ counts,
    int n_edges, int nproj)
{
  __shared__ __align__(16) short wlds[32 * 64 * 8];   // 32 KB: [ctile*4+kk][lane][8]
  __shared__ __align__(16) short walds[4 * 64 * 8];   // 4 KB:  [kk][lane][8]

  if (blockIdx.x >= nproj) {
    // ---- count role: 4 edges per thread via int4 (fire-and-forget atomics)
    int e = ((blockIdx.x - nproj) * 256 + threadIdx.x) * 4;
    if (e + 4 <= n_edges) {
      const int4 d = *(const int4*)(e_dst + e);
      atomicAdd(&counts[d.x], 1);
      atomicAdd(&counts[d.y], 1);
      atomicAdd(&counts[d.z], 1);
      atomicAdd(&counts[d.w], 1);
    } else {
      for (; e < n_edges; ++e) atomicAdd(&counts[e_dst[e]], 1);
    }
    return;
  }

  const int t    = threadIdx.x;
  const int l    = t & 63;        // lane in wave
  const int il   = l & 15;
  const int quad = l >> 4;
  const int wbase = blockIdx.x * 128 + (t >> 6) * 32;   // wave's 32 rows

  // ---- stage W into LDS in B-fragment order (bf16)
  for (int idx = t; idx < 2048; idx += 256) {
    const int tile = idx >> 6;          // ctile*4 + kk
    const int l2   = idx & 63;
    const int c    = tile >> 2;
    const int kk   = tile & 3;
    const int q2   = l2 >> 4;
    const int i2   = l2 & 15;
    const float* wp = W + (size_t)(kk * 32 + q2 * 8) * 128 + c * 16 + i2;
    bf16x8 wv;
    #pragma unroll
    for (int j = 0; j < 8; ++j) wv[j] = (short)f2bf(wp[(size_t)j * 128]);
    *(bf16x8*)(wlds + idx * 8) = wv;
  }

  // ---- stage wa (attention-scalar col-tile): one (kk,lane) per thread
  {
    const int kk = t >> 6;
    const int l2 = t & 63;
    const int q2 = l2 >> 4;
    const int i2 = l2 & 15;
    bf16x8 wv = {0, 0, 0, 0, 0, 0, 0, 0};
    if (i2 < 8) {
      const int head = i2 >> 1;
      const float* ap = (i2 & 1) ? a_dst : a_src;
      #pragma unroll
      for (int j = 0; j < 8; ++j) {
        const int k = kk * 32 + q2 * 8 + j;
        const float* wr = W + (size_t)k * 128 + head * 32;
        float sum = 0.f;
        for (int d = 0; d < 32; d += 4) {
          const float4 wq = *(const float4*)(wr + d);
          const float4 aq = *(const float4*)(ap + d);
          sum += wq.x * aq.x + wq.y * aq.y + wq.z * aq.z + wq.w * aq.w;
        }
        wv[j] = (short)f2bf(sum);
      }
    }
    *(bf16x8*)(walds + t * 8) = wv;
  }

  // ---- load + convert A fragments (x rows), split hi/lo bf16
  bf16x8 ahi[2][4], alo[2][4];
  #pragma unroll
  for (int rt = 0; rt < 2; ++rt) {
    int row = wbase + rt * 16 + il;
    if (row > n_nodes - 1) row = n_nodes - 1;    // clamp (dup row, stores guarded)
    #pragma unroll
    for (int kk = 0; kk < 4; ++kk) {
      const float* p = x + (size_t)row * 128 + kk * 32 + quad * 8;
      const float4 u0 = *(const float4*)(p);
      const float4 u1 = *(const float4*)(p + 4);
      float f[8] = {u0.x, u0.y, u0.z, u0.w, u1.x, u1.y, u1.z, u1.w};
      #pragma unroll
      for (int j = 0; j < 8; ++j) {
        const unsigned short hb = f2bf(f[j]);
        ahi[rt][kk][j] = (short)hb;
        alo[rt][kk][j] = (short)f2bf(f[j] - bf2f(hb));
      }
    }
  }

  __syncthreads();

  // ---- MFMA main: acc[rt][c] over 8 col-tiles, K=128 in 4 steps, 2 terms
  f32x4 acc[2][8] = {};
  #pragma unroll
  for (int c = 0; c < 8; ++c) {
    #pragma unroll
    for (int kk = 0; kk < 4; ++kk) {
      const bf16x8 b = *(const bf16x8*)(wlds + ((c * 4 + kk) * 64 + l) * 8);
      acc[0][c] = __builtin_amdgcn_mfma_f32_16x16x32_bf16(ahi[0][kk], b, acc[0][c], 0, 0, 0);
      acc[0][c] = __builtin_amdgcn_mfma_f32_16x16x32_bf16(alo[0][kk], b, acc[0][c], 0, 0, 0);
      acc[1][c] = __builtin_amdgcn_mfma_f32_16x16x32_bf16(ahi[1][kk], b, acc[1][c], 0, 0, 0);
      acc[1][c] = __builtin_amdgcn_mfma_f32_16x16x32_bf16(alo[1][kk], b, acc[1][c], 0, 0, 0);
    }
  }
  // ---- attention-scalar col-tile
  f32x4 acc2[2] = {};
  #pragma unroll
  for (int kk = 0; kk < 4; ++kk) {
    const bf16x8 bv = *(const bf16x8*)(walds + (kk * 64 + l) * 8);
    acc2[0] = __builtin_amdgcn_mfma_f32_16x16x32_bf16(ahi[0][kk], bv, acc2[0], 0, 0, 0);
    acc2[0] = __builtin_amdgcn_mfma_f32_16x16x32_bf16(alo[0][kk], bv, acc2[0], 0, 0, 0);
    acc2[1] = __builtin_amdgcn_mfma_f32_16x16x32_bf16(ahi[1][kk], bv, acc2[1], 0, 0, 0);
    acc2[1] = __builtin_amdgcn_mfma_f32_16x16x32_bf16(alo[1][kk], bv, acc2[1], 0, 0, 0);
  }

  // ---- epilogue: pack h to bf16 pairs across il-neighbors, store uint2;
  //      write sc[row][il] for il<8.
  #pragma unroll
  for (int rt = 0; rt < 2; ++rt) {
    #pragma unroll
    for (int reg = 0; reg < 4; ++reg) {
      const int r = wbase + rt * 16 + quad * 4 + reg;
      const bool inb = (r < n_nodes);
      const bool wr = inb && ((il & 3) == 0);
      #pragma unroll
      for (int c = 0; c < 8; ++c) {
        const float v  = acc[rt][c][reg];
        const float vn = __shfl_xor(v, 1);
        const float plo = (il & 1) ? vn : v;
        const float phi = (il & 1) ? v : vn;
        const unsigned px = pack_bf16(plo, phi);     // pair (il&~1, il&~1+1)
        const unsigned py = __shfl_xor(px, 2);       // pair from il^2
        if (wr) {
          uint2 u; u.x = px; u.y = py;
          *(uint2*)(h + (size_t)r * 64 + c * 8 + (il >> 1)) = u;
        }
      }
      if (inb && il < 8) sc[(size_t)r * 8 + il] = acc2[rt][reg];
    }
  }
}

// ---------------------------------------------------------------------------
// k_scan: single-dispatch exclusive scan of counts -> row_start (+cursor),
// decoupled lookback. desc[b] packs (flag<<62)|value: 1=AGG, 2=INC, 0=invalid
// (memset). All 98 blocks co-resident (<< 256 CUs) -> lookback terminates.
// ---------------------------------------------------------------------------
__global__ __launch_bounds__(256) void k_scan(
    const int* __restrict__ counts, int n, int n_edges,
    int* __restrict__ row_start, int* __restrict__ cursor,
    unsigned long long* __restrict__ desc)
{
  __shared__ int sdata[256];
  __shared__ int s_prefix;
  const int b = blockIdx.x, t = threadIdx.x;
  const int base = b * 1024 + t * 4;
  const int v0 = (base+0 < n) ? counts[base+0] : 0;
  const int v1 = (base+1 < n) ? counts[base+1] : 0;
  const int v2 = (base+2 < n) ? counts[base+2] : 0;
  const int v3 = (base+3 < n) ? counts[base+3] : 0;
  const int tsum = v0 + v1 + v2 + v3;
  sdata[t] = tsum;
  __syncthreads();
  for (int off = 1; off < 256; off <<= 1) {
    const int addv = (t >= off) ? sdata[t - off] : 0;
    __syncthreads();
    sdata[t] += addv;
    __syncthreads();
  }
  const int block_total = sdata[255];
  const int local_excl  = sdata[t] - tsum;

  if (t == 0) {
    if (b == 0) {
      atomicExch(&desc[0], (2ULL << 62) | (unsigned long long)block_total);
      s_prefix = 0;
    } else {
      atomicExch(&desc[b], (1ULL << 62) | (unsigned long long)block_total);
    }
  }

  if (b > 0 && t < 64) {
    int jbase = b - 1;
    int accum = 0;
    for (;;) {
      const int j = jbase - t;
      unsigned long long d = (j >= 0) ? atomicAdd(&desc[j], 0ULL) : (2ULL << 62);
      const unsigned flag = (unsigned)(d >> 62);
      const unsigned long long m_inc  = __ballot(flag == 2);
      const unsigned long long m_zero = __ballot(flag == 0);
      const int kinc = (m_inc == 0) ? 64 : (__ffsll((long long)m_inc) - 1);
      const unsigned long long below = (kinc >= 64) ? ~0ULL : ((1ULL << kinc) - 1ULL);
      if (m_zero & below) continue;
      int contrib = (t <= kinc) ? (int)(d & 0x3FFFFFFFFFFFFFFFULL) : 0;
      #pragma unroll
      for (int off = 32; off; off >>= 1) contrib += __shfl_xor(contrib, off);
      accum += contrib;
      if (kinc < 64) break;
      jbase -= 64;
    }
    if (t == 0) {
      s_prefix = accum;
      atomicExch(&desc[b], (2ULL << 62) | (unsigned long long)(accum + block_total));
    }
  }
  __syncthreads();
  const int prefix = s_prefix;

  int excl = prefix + local_excl;
  if (base+0 < n) { row_start[base+0] = excl; cursor[base+0] = excl; }  excl += v0;
  if (base+1 < n) { row_start[base+1] = excl; cursor[base+1] = excl; }  excl += v1;
  if (base+2 < n) { row_start[base+2] = excl; cursor[base+2] = excl; }  excl += v2;
  if (base+3 < n) { row_start[base+3] = excl; cursor[base+3] = excl; }
  if (b == 0 && t == 0) row_start[n] = n_edges;
}

// ---------------------------------------------------------------------------
// k_fill: CSR fill, 1 edge/thread (returning atomics want TLP).
// ---------------------------------------------------------------------------
__global__ void k_fill(const int* __restrict__ src, const int* __restrict__ dst,
                       int* __restrict__ cursor, int* __restrict__ csr_src, int n_edges) {
  const int e = blockIdx.x * 256 + threadIdx.x;
  if (e < n_edges) {
    const int pos = atomicAdd(&cursor[dst[e]], 1);
    csr_src[pos] = src[e];
  }
}

// unpack-fma helper: 8 bf16 (uint4) * alpha into acc[8]
#define ACC_EDGE(al, hv)                              \
  acc[0] = fmaf(al, bf_lo(hv.x), acc[0]);             \
  acc[1] = fmaf(al, bf_hi(hv.x), acc[1]);             \
  acc[2] = fmaf(al, bf_lo(hv.y), acc[2]);             \
  acc[3] = fmaf(al, bf_hi(hv.y), acc[3]);             \
  acc[4] = fmaf(al, bf_lo(hv.z), acc[4]);             \
  acc[5] = fmaf(al, bf_hi(hv.z), acc[5]);             \
  acc[6] = fmaf(al, bf_hi(hv.w) * 0.f + bf_lo(hv.w), acc[6]); \
  acc[7] = fmaf(al, bf_hi(hv.w), acc[7]);

// ---------------------------------------------------------------------------
// k_agg v3: 16 lanes per node (wave = 4 nodes, block 256 = 16 nodes).
// Lane g in [0,16): owns 8 channels d = 8g..8g+7 (head = g>>2).
// Phase A: 4 lanes per head do online softmax over strided edges, stashing
//          s AND src for edges 0..15 in 4 regs each; shfl-merge (xor 1,2).
// Alpha precompute: 4 expf/lane cover all 16 stashed edges -> Phase B has
//          ZERO expf for deg<=16 (99.7% of Poisson(8) nodes).
// Phase B: groups of 4 edges; alpha/src via shfl from stash; uint4 gather
//          (8 bf16/lane). deg>16 tail recomputes inline.
// Epilogue: residual + LayerNorm (16-lane shfl) + ELU. No LDS/atomics.
// ---------------------------------------------------------------------------
__global__ __launch_bounds__(256) void k_agg(
    const unsigned* __restrict__ h, const float* __restrict__ sc,
    const int* __restrict__ row_start, const int* __restrict__ csr_src,
    const float* __restrict__ x, const float* __restrict__ gamma,
    const float* __restrict__ beta, float* __restrict__ out, int n_nodes)
{
  const int t    = threadIdx.x;
  const int lane = t & 63;
  const int g    = lane & 15;
  const int node = blockIdx.x * 16 + (t >> 6) * 4 + (lane >> 4);
  if (node >= n_nodes) return;           // uniform per 16-lane group
  const int head = g >> 2;
  const int sub  = g & 3;
  const int hh   = head * 2;
  const int beg  = row_start[node];
  const int deg  = row_start[node + 1] - beg;
  const float sdv = sc[node * 8 + hh + 1];

  // Phase A: online max/sum, stash s+src for edges sub, sub+4, sub+8, sub+12
  float m = -INFINITY, l = 0.f;
  float t0 = 0.f, t1 = 0.f, t2 = 0.f, t3 = 0.f;
  int   c0 = 0,   c1 = 0,   c2 = 0,   c3 = 0;
  if (sub < deg) {
    c0 = csr_src[beg + sub];
    float s = sc[c0 * 8 + hh] + sdv;  s = s > 0.f ? s : NEG_SLOPE * s;
    t0 = s; m = s; l = 1.f;
  }
  if (sub + 4 < deg) {
    c1 = csr_src[beg + sub + 4];
    float s = sc[c1 * 8 + hh] + sdv;  s = s > 0.f ? s : NEG_SLOPE * s;
    t1 = s;
    const float mn = fmaxf(m, s);
    l = l * __expf(m - mn) + __expf(s - mn);  m = mn;
  }
  if (sub + 8 < deg) {
    c2 = csr_src[beg + sub + 8];
    float s = sc[c2 * 8 + hh] + sdv;  s = s > 0.f ? s : NEG_SLOPE * s;
    t2 = s;
    const float mn = fmaxf(m, s);
    l = l * __expf(m - mn) + __expf(s - mn);  m = mn;
  }
  if (sub + 12 < deg) {
    c3 = csr_src[beg + sub + 12];
    float s = sc[c3 * 8 + hh] + sdv;  s = s > 0.f ? s : NEG_SLOPE * s;
    t3 = s;
    const float mn = fmaxf(m, s);
    l = l * __expf(m - mn) + __expf(s - mn);  m = mn;
  }
  for (int i = sub + 16; i < deg; i += 4) {      // rare (deg>16)
    const int cs = csr_src[beg + i];
    float s = sc[cs * 8 + hh] + sdv;  s = s > 0.f ? s : NEG_SLOPE * s;
    const float mn = fmaxf(m, s);
    l = l * __expf(m - mn) + __expf(s - mn);  m = mn;
  }
  // merge within 4-lane head group
  #pragma unroll
  for (int off = 1; off < 4; off <<= 1) {
    const float m2 = __shfl_xor(m, off);
    const float l2 = __shfl_xor(l, off);
    const float mn = fmaxf(m, m2);
    if (mn == -INFINITY) { m = -INFINITY; l = 0.f; }
    else {
      l = l * __expf(m - mn) + l2 * __expf(m2 - mn);
      m = mn;
    }
  }
  const float inv_l = (deg > 0) ? 1.f / l : 0.f;
  // alpha precompute for stashed edges (garbage where unused; never read)
  const float a0 = __expf(t0 - m) * inv_l;
  const float a1 = __expf(t1 - m) * inv_l;
  const float a2 = __expf(t2 - m) * inv_l;
  const float a3 = __expf(t3 - m) * inv_l;

  const int base3 = lane & 60;           // this lane's head-stash lane base

  // Phase B: weighted gather, groups of 4 stashed edges
  float acc[8] = {0.f, 0.f, 0.f, 0.f, 0.f, 0.f, 0.f, 0.f};
  const int deg16 = deg < 16 ? deg : 16;
  #pragma unroll
  for (int r = 0; r < 4; ++r) {
    const int i0 = r * 4;
    if (i0 >= deg16) break;              // uniform per node group
    const float ar = r == 0 ? a0 : r == 1 ? a1 : r == 2 ? a2 : a3;
    const int   cr = r == 0 ? c0 : r == 1 ? c1 : r == 2 ? c2 : c3;
    const int   n  = deg16 - i0;
    {
      const float al = __shfl(ar, base3 | 0);
      const int   sr = __shfl(cr, base3 | 0);
      const uint4 hv = *(const uint4*)(h + (size_t)sr * 64 + g * 4);
      ACC_EDGE(al, hv)
    }
    if (n > 1) {
      const float al = __shfl(ar, base3 | 1);
      const int   sr = __shfl(cr, base3 | 1);
      const uint4 hv = *(const uint4*)(h + (size_t)sr * 64 + g * 4);
      ACC_EDGE(al, hv)
    }
    if (n > 2) {
      const float al = __shfl(ar, base3 | 2);
      const int   sr = __shfl(cr, base3 | 2);
      const uint4 hv = *(const uint4*)(h + (size_t)sr * 64 + g * 4);
      ACC_EDGE(al, hv)
    }
    if (n > 3) {
      const float al = __shfl(ar, base3 | 3);
      const int   sr = __shfl(cr, base3 | 3);
      const uint4 hv = *(const uint4*)(h + (size_t)sr * 64 + g * 4);
      ACC_EDGE(al, hv)
    }
  }
  for (int i = 16; i < deg; ++i) {       // rare tail (deg>16), inline compute
    const int sr = csr_src[beg + i];
    float s = sc[sr * 8 + hh] + sdv;  s = s > 0.f ? s : NEG_SLOPE * s;
    const float al = __expf(s - m) * inv_l;
    const uint4 hv = *(const uint4*)(h + (size_t)sr * 64 + g * 4);
    ACC_EDGE(al, hv)
  }

  // residual + LayerNorm + ELU (within the 16-lane node group)
  const float4 xa = *(const float4*)(x + (size_t)node * 128 + g * 8);
  const float4 xb = *(const float4*)(x + (size_t)node * 128 + g * 8 + 4);
  float rr[8];
  rr[0] = acc[0] + xa.x;  rr[1] = acc[1] + xa.y;
  rr[2] = acc[2] + xa.z;  rr[3] = acc[3] + xa.w;
  rr[4] = acc[4] + xb.x;  rr[5] = acc[5] + xb.y;
  rr[6] = acc[6] + xb.z;  rr[7] = acc[7] + xb.w;
  float s1 = 0.f, s2 = 0.f;
  #pragma unroll
  for (int j = 0; j < 8; ++j) { s1 += rr[j]; s2 += rr[j] * rr[j]; }
  #pragma unroll
  for (int off = 1; off < 16; off <<= 1) {   // xor stays within 16-group
    s1 += __shfl_xor(s1, off);
    s2 += __shfl_xor(s2, off);
  }
  const float mu   = s1 * (1.f / 128.f);
  const float var  = s2 * (1.f / 128.f) - mu * mu;
  const float rstd = rsqrtf(var + LN_EPS);
  const float4 ga = *(const float4*)(gamma + g * 8);
  const float4 gb = *(const float4*)(gamma + g * 8 + 4);
  const float4 ba = *(const float4*)(beta  + g * 8);
  const float4 bb = *(const float4*)(beta  + g * 8 + 4);
  float4 o0, o1;
  o0.x = (rr[0] - mu) * rstd * ga.x + ba.x;
  o0.y = (rr[1] - mu) * rstd * ga.y + ba.y;
  o0.z = (rr[2] - mu) * rstd * ga.z + ba.z;
  o0.w = (rr[3] - mu) * rstd * ga.w + ba.w;
  o1.x = (rr[4] - mu) * rstd * gb.x + bb.x;
  o1.y = (rr[5] - mu) * rstd * gb.y + bb.y;
  o1.z = (rr[6] - mu) * rstd * gb.z + bb.z;
  o1.w = (rr[7] - mu) * rstd * gb.w + bb.w;
  o0.x = o0.x > 0.f ? o0.x : expm1f(o0.x);
  o0.y = o0.y > 0.f ? o0.y : expm1f(o0.y);
  o0.z = o0.z > 0.f ? o0.z : expm1f(o0.z);
  o0.w = o0.w > 0.f ? o0.w : expm1f(o0.w);
  o1.x = o1.x > 0.f ? o1.x : expm1f(o1.x);
  o1.y = o1.y > 0.f ? o1.y : expm1f(o1.y);
  o1.z = o1.z > 0.f ? o1.z : expm1f(o1.z);
  o1.w = o1.w > 0.f ? o1.w : expm1f(o1.w);
  *(float4*)(out + (size_t)node * 128 + g * 8)     = o0;
  *(float4*)(out + (size_t)node * 128 + g * 8 + 4) = o1;
}

// ---------------------------------------------------------------------------
extern "C" void kernel_launch(void* const* d_in, const int* in_sizes, int n_in,
                              void* d_out, int out_size, void* d_ws, size_t ws_size,
                              hipStream_t stream)
{
  const float* x    = (const float*)d_in[0];
  const int*   ei   = (const int*)d_in[1];
  const float* W    = (const float*)d_in[2];
  const float* a_s  = (const float*)d_in[3];
  const float* a_d  = (const float*)d_in[4];
  const float* gam  = (const float*)d_in[5];
  const float* bet  = (const float*)d_in[6];
  float* out = (float*)d_out;

  const int n_nodes = in_sizes[0] / 128;
  const int n_edges = in_sizes[1] / 2;
  const int* e_src = ei;
  const int* e_dst = ei + n_edges;

  const int nblk = (n_nodes + 1023) / 1024;    // scan blocks

  // workspace carve-up (~34 MB). counts+desc contiguous for one memset.
  char* p = (char*)d_ws;
  unsigned* h = (unsigned*)p; p += (size_t)n_nodes * 64 * sizeof(unsigned);  // bf16-packed
  float* sc   = (float*)p;  p += (size_t)n_nodes * 8 * sizeof(float);        // [ssrc|sdst] x 4 heads
  int* counts = (int*)p;    p += (size_t)((n_nodes + 1) & ~1) * sizeof(int); // 8B-align next
  unsigned long long* desc = (unsigned long long*)p; p += (size_t)nblk * sizeof(unsigned long long);
  int* row_start = (int*)p; p += (size_t)(n_nodes + 4) * sizeof(int);
  int* cursor    = (int*)p; p += (size_t)n_nodes * sizeof(int);
  int* csr_src   = (int*)p; p += (size_t)n_edges * sizeof(int);

  const size_t zero_bytes = (char*)(desc + nblk) - (char*)counts;
  hipMemsetAsync(counts, 0, zero_bytes, stream);

  const int nproj  = (n_nodes + 127) / 128;
  const int ncount = (n_edges + 1023) / 1024;
  k_proj_count<<<nproj + ncount, 256, 0, stream>>>(
      x, W, a_s, a_d, h, sc, n_nodes, e_dst, counts, n_edges, nproj);
  k_scan<<<nblk, 256, 0, stream>>>(counts, n_nodes, n_edges, row_start, cursor, desc);
  k_fill<<<(n_edges + 255) / 256, 256, 0, stream>>>(e_src, e_dst, cursor, csr_src, n_edges);
  k_agg<<<(n_nodes + 15) / 16, 256, 0, stream>>>(h, sc, row_start, csr_src, x, gam, bet, out, n_nodes);
}

// Round 6
// 251.327 us; speedup vs baseline: 1.1393x; 1.1393x over previous
//
#include <hip/hip_runtime.h>
#include <math.h>

#define NEG_SLOPE 0.2f
#define LN_EPS 1e-5f

typedef __attribute__((ext_vector_type(8))) short bf16x8;
typedef __attribute__((ext_vector_type(4))) float f32x4;

// fp32 -> bf16 (RTNE)
static __device__ __forceinline__ unsigned short f2bf(float f) {
  unsigned u = __float_as_uint(f);
  u += 0x7fffu + ((u >> 16) & 1u);
  return (unsigned short)(u >> 16);
}
// pack two fp32 into bf16x2 (RTNE), elem0 in low half
static __device__ __forceinline__ unsigned pack_bf16(float a, float b) {
  unsigned ua = __float_as_uint(a);
  unsigned ub = __float_as_uint(b);
  ua += 0x7fffu + ((ua >> 16) & 1u);
  ub += 0x7fffu + ((ub >> 16) & 1u);
  return (ua >> 16) | (ub & 0xffff0000u);
}
static __device__ __forceinline__ float bf_lo(unsigned u) { return __uint_as_float(u << 16); }
static __device__ __forceinline__ float bf_hi(unsigned u) { return __uint_as_float(u & 0xffff0000u); }

// ---------------------------------------------------------------------------
// k_prep: one-time conversions (block-invariant data), 9 blocks.
//  Blocks 0..7: W (fp32 [128][128]) -> wfrag bf16 in MFMA B-fragment order:
//     wfrag[(ctile*4+kk)*64 + lane][j] = bf16(W[kk*32 + (lane>>4)*8 + j][ctile*16 + (lane&15)])
//  Block 8: wa col-tile (attention scalars): wa[k][n], n = head*2 + (0=src,1=dst):
//     wafrag[(kk*64+lane)][j] = bf16(sum_d W[k][head*32+d] * a_{src|dst}[d])
// ---------------------------------------------------------------------------
__global__ __launch_bounds__(256) void k_prep(
    const float* __restrict__ W, const float* __restrict__ a_src,
    const float* __restrict__ a_dst, short* __restrict__ wfrag,
    short* __restrict__ wafrag)
{
  const int t = threadIdx.x;
  if (blockIdx.x < 8) {
    const int idx  = blockIdx.x * 256 + t;   // 0..2047
    const int tile = idx >> 6;               // ctile*4 + kk
    const int l2   = idx & 63;
    const int c    = tile >> 2;
    const int kk   = tile & 3;
    const int q2   = l2 >> 4;
    const int i2   = l2 & 15;
    const float* wp = W + (size_t)(kk * 32 + q2 * 8) * 128 + c * 16 + i2;
    bf16x8 wv;
    #pragma unroll
    for (int j = 0; j < 8; ++j) wv[j] = (short)f2bf(wp[(size_t)j * 128]);
    *(bf16x8*)(wfrag + (size_t)idx * 8) = wv;
  } else {
    const int kk = t >> 6;
    const int l2 = t & 63;
    const int q2 = l2 >> 4;
    const int i2 = l2 & 15;
    bf16x8 wv = {0, 0, 0, 0, 0, 0, 0, 0};
    if (i2 < 8) {
      const int head = i2 >> 1;
      const float* ap = (i2 & 1) ? a_dst : a_src;
      #pragma unroll
      for (int j = 0; j < 8; ++j) {
        const int k = kk * 32 + q2 * 8 + j;
        const float* wr = W + (size_t)k * 128 + head * 32;
        float sum = 0.f;
        for (int d = 0; d < 32; d += 4) {
          const float4 wq = *(const float4*)(wr + d);
          const float4 aq = *(const float4*)(ap + d);
          sum += wq.x * aq.x + wq.y * aq.y + wq.z * aq.z + wq.w * aq.w;
        }
        wv[j] = (short)f2bf(sum);
      }
    }
    *(bf16x8*)(wafrag + (size_t)t * 8) = wv;
  }
}

// ---------------------------------------------------------------------------
// k_proj_count: MFMA projection (split-bf16: h = x_hi@W + x_lo@W, hi=trunc,
// lo=RTNE of remainder) + fused attention-scalar col-tile (sc) + count role.
//  Proj blocks: 128 rows (4 waves x 2 row-tiles of 16). W/wa staged by plain
//  16 B/thread vector copies from the pre-converted fragment buffers.
//  kk-outer main loop: A-fragments live only per kk-slice (16 VGPR) so the
//  kernel fits 4 waves/SIMD (launch_bounds min-waves=4).
//  mfma_f32_16x16x32_bf16 layouts (HW-verified, guide §3):
//    A: lane holds A[m=lane&15][k=(lane>>4)*8+j]   (j=0..7)
//    B: lane holds B[k=(lane>>4)*8+j][n=lane&15]
//    C/D: lane holds D[row=(lane>>4)*4+reg][col=lane&15]
// ---------------------------------------------------------------------------
__global__ __launch_bounds__(256, 4) void k_proj_count(
    const float* __restrict__ x, const short* __restrict__ wfrag,
    const short* __restrict__ wafrag,
    unsigned* __restrict__ h, float* __restrict__ sc, int n_nodes,
    const int* __restrict__ e_dst, int* __restrict__ counts,
    int n_edges, int nproj)
{
  __shared__ __align__(16) short wlds[32 * 64 * 8];   // 32 KB: [ctile*4+kk][lane][8]
  __shared__ __align__(16) short walds[4 * 64 * 8];   // 4 KB:  [kk][lane][8]

  if (blockIdx.x >= nproj) {
    // ---- count role: 4 edges per thread via int4 (fire-and-forget atomics)
    int e = ((blockIdx.x - nproj) * 256 + threadIdx.x) * 4;
    if (e + 4 <= n_edges) {
      const int4 d = *(const int4*)(e_dst + e);
      atomicAdd(&counts[d.x], 1);
      atomicAdd(&counts[d.y], 1);
      atomicAdd(&counts[d.z], 1);
      atomicAdd(&counts[d.w], 1);
    } else {
      for (; e < n_edges; ++e) atomicAdd(&counts[e_dst[e]], 1);
    }
    return;
  }

  const int t    = threadIdx.x;
  const int l    = t & 63;        // lane in wave
  const int il   = l & 15;
  const int quad = l >> 4;
  const int wbase = blockIdx.x * 128 + (t >> 6) * 32;   // wave's 32 rows

  // ---- stage W/wa fragment buffers into LDS (pure vector copies)
  {
    const uint4* wf4 = (const uint4*)wfrag;
    uint4* wl4 = (uint4*)wlds;
    #pragma unroll
    for (int i = 0; i < 8; ++i) wl4[t + i * 256] = wf4[t + i * 256];
    ((uint4*)walds)[t] = ((const uint4*)wafrag)[t];
  }
  __syncthreads();

  // ---- kk-outer MFMA main loop
  f32x4 acc[2][8] = {};
  f32x4 acc2[2] = {};
  #pragma unroll
  for (int kk = 0; kk < 4; ++kk) {
    bf16x8 ahi[2], alo[2];
    #pragma unroll
    for (int rt = 0; rt < 2; ++rt) {
      int row = wbase + rt * 16 + il;
      if (row > n_nodes - 1) row = n_nodes - 1;    // clamp (dup row, stores guarded)
      const float* p = x + (size_t)row * 128 + kk * 32 + quad * 8;
      const float4 u0 = *(const float4*)(p);
      const float4 u1 = *(const float4*)(p + 4);
      const float f[8] = {u0.x, u0.y, u0.z, u0.w, u1.x, u1.y, u1.z, u1.w};
      #pragma unroll
      for (int j = 0; j < 8; ++j) {
        const unsigned u = __float_as_uint(f[j]);
        ahi[rt][j] = (short)(u >> 16);                       // trunc hi
        const float lof = f[j] - __uint_as_float(u & 0xffff0000u);
        alo[rt][j] = (short)f2bf(lof);                       // RTNE lo
      }
    }
    #pragma unroll
    for (int c = 0; c < 8; ++c) {
      const bf16x8 b = *(const bf16x8*)(wlds + ((c * 4 + kk) * 64 + l) * 8);
      acc[0][c] = __builtin_amdgcn_mfma_f32_16x16x32_bf16(ahi[0], b, acc[0][c], 0, 0, 0);
      acc[0][c] = __builtin_amdgcn_mfma_f32_16x16x32_bf16(alo[0], b, acc[0][c], 0, 0, 0);
      acc[1][c] = __builtin_amdgcn_mfma_f32_16x16x32_bf16(ahi[1], b, acc[1][c], 0, 0, 0);
      acc[1][c] = __builtin_amdgcn_mfma_f32_16x16x32_bf16(alo[1], b, acc[1][c], 0, 0, 0);
    }
    const bf16x8 bv = *(const bf16x8*)(walds + (kk * 64 + l) * 8);
    acc2[0] = __builtin_amdgcn_mfma_f32_16x16x32_bf16(ahi[0], bv, acc2[0], 0, 0, 0);
    acc2[0] = __builtin_amdgcn_mfma_f32_16x16x32_bf16(alo[0], bv, acc2[0], 0, 0, 0);
    acc2[1] = __builtin_amdgcn_mfma_f32_16x16x32_bf16(ahi[1], bv, acc2[1], 0, 0, 0);
    acc2[1] = __builtin_amdgcn_mfma_f32_16x16x32_bf16(alo[1], bv, acc2[1], 0, 0, 0);
  }

  // ---- epilogue: pack h to bf16 pairs across il-neighbors, store uint2;
  //      write sc[row][il] for il<8.
  #pragma unroll
  for (int rt = 0; rt < 2; ++rt) {
    #pragma unroll
    for (int reg = 0; reg < 4; ++reg) {
      const int r = wbase + rt * 16 + quad * 4 + reg;
      const bool inb = (r < n_nodes);
      const bool wr = inb && ((il & 3) == 0);
      #pragma unroll
      for (int c = 0; c < 8; ++c) {
        const float v  = acc[rt][c][reg];
        const float vn = __shfl_xor(v, 1);
        const float plo = (il & 1) ? vn : v;
        const float phi = (il & 1) ? v : vn;
        const unsigned px = pack_bf16(plo, phi);     // pair (il&~1, il&~1+1)
        const unsigned py = __shfl_xor(px, 2);       // pair from il^2
        if (wr) {
          uint2 u; u.x = px; u.y = py;
          *(uint2*)(h + (size_t)r * 64 + c * 8 + (il >> 1)) = u;
        }
      }
      if (inb && il < 8) sc[(size_t)r * 8 + il] = acc2[rt][reg];
    }
  }
}

// ---------------------------------------------------------------------------
// k_scan: single-dispatch exclusive scan of counts -> row_start (+cursor),
// decoupled lookback. desc[b] packs (flag<<62)|value: 1=AGG, 2=INC, 0=invalid
// (memset). All 98 blocks co-resident (<< 256 CUs) -> lookback terminates.
// ---------------------------------------------------------------------------
__global__ __launch_bounds__(256) void k_scan(
    const int* __restrict__ counts, int n, int n_edges,
    int* __restrict__ row_start, int* __restrict__ cursor,
    unsigned long long* __restrict__ desc)
{
  __shared__ int sdata[256];
  __shared__ int s_prefix;
  const int b = blockIdx.x, t = threadIdx.x;
  const int base = b * 1024 + t * 4;
  const int v0 = (base+0 < n) ? counts[base+0] : 0;
  const int v1 = (base+1 < n) ? counts[base+1] : 0;
  const int v2 = (base+2 < n) ? counts[base+2] : 0;
  const int v3 = (base+3 < n) ? counts[base+3] : 0;
  const int tsum = v0 + v1 + v2 + v3;
  sdata[t] = tsum;
  __syncthreads();
  for (int off = 1; off < 256; off <<= 1) {
    const int addv = (t >= off) ? sdata[t - off] : 0;
    __syncthreads();
    sdata[t] += addv;
    __syncthreads();
  }
  const int block_total = sdata[255];
  const int local_excl  = sdata[t] - tsum;

  if (t == 0) {
    if (b == 0) {
      atomicExch(&desc[0], (2ULL << 62) | (unsigned long long)block_total);
      s_prefix = 0;
    } else {
      atomicExch(&desc[b], (1ULL << 62) | (unsigned long long)block_total);
    }
  }

  if (b > 0 && t < 64) {
    int jbase = b - 1;
    int accum = 0;
    for (;;) {
      const int j = jbase - t;
      unsigned long long d = (j >= 0) ? atomicAdd(&desc[j], 0ULL) : (2ULL << 62);
      const unsigned flag = (unsigned)(d >> 62);
      const unsigned long long m_inc  = __ballot(flag == 2);
      const unsigned long long m_zero = __ballot(flag == 0);
      const int kinc = (m_inc == 0) ? 64 : (__ffsll((long long)m_inc) - 1);
      const unsigned long long below = (kinc >= 64) ? ~0ULL : ((1ULL << kinc) - 1ULL);
      if (m_zero & below) continue;
      int contrib = (t <= kinc) ? (int)(d & 0x3FFFFFFFFFFFFFFFULL) : 0;
      #pragma unroll
      for (int off = 32; off; off >>= 1) contrib += __shfl_xor(contrib, off);
      accum += contrib;
      if (kinc < 64) break;
      jbase -= 64;
    }
    if (t == 0) {
      s_prefix = accum;
      atomicExch(&desc[b], (2ULL << 62) | (unsigned long long)(accum + block_total));
    }
  }
  __syncthreads();
  const int prefix = s_prefix;

  int excl = prefix + local_excl;
  if (base+0 < n) { row_start[base+0] = excl; cursor[base+0] = excl; }  excl += v0;
  if (base+1 < n) { row_start[base+1] = excl; cursor[base+1] = excl; }  excl += v1;
  if (base+2 < n) { row_start[base+2] = excl; cursor[base+2] = excl; }  excl += v2;
  if (base+3 < n) { row_start[base+3] = excl; cursor[base+3] = excl; }
  if (b == 0 && t == 0) row_start[n] = n_edges;
}

// ---------------------------------------------------------------------------
// k_fill: CSR fill, 1 edge/thread (returning atomics want TLP).
// ---------------------------------------------------------------------------
__global__ void k_fill(const int* __restrict__ src, const int* __restrict__ dst,
                       int* __restrict__ cursor, int* __restrict__ csr_src, int n_edges) {
  const int e = blockIdx.x * 256 + threadIdx.x;
  if (e < n_edges) {
    const int pos = atomicAdd(&cursor[dst[e]], 1);
    csr_src[pos] = src[e];
  }
}

// unpack-fma helper: 8 bf16 (uint4) * alpha into acc[8]
#define ACC_EDGE(al, hv)                              \
  acc[0] = fmaf(al, bf_lo(hv.x), acc[0]);             \
  acc[1] = fmaf(al, bf_hi(hv.x), acc[1]);             \
  acc[2] = fmaf(al, bf_lo(hv.y), acc[2]);             \
  acc[3] = fmaf(al, bf_hi(hv.y), acc[3]);             \
  acc[4] = fmaf(al, bf_lo(hv.z), acc[4]);             \
  acc[5] = fmaf(al, bf_hi(hv.z), acc[5]);             \
  acc[6] = fmaf(al, bf_lo(hv.w), acc[6]);             \
  acc[7] = fmaf(al, bf_hi(hv.w), acc[7]);

// ---------------------------------------------------------------------------
// k_agg v3: 16 lanes per node (wave = 4 nodes, block 256 = 16 nodes).
// Lane g in [0,16): owns 8 channels d = 8g..8g+7 (head = g>>2).
// Phase A: 4 lanes per head do online softmax over strided edges, stashing
//          s AND src for edges 0..15 in 4 regs each; shfl-merge (xor 1,2).
// Alpha precompute: 4 expf/lane cover all 16 stashed edges -> Phase B has
//          ZERO expf for deg<=16 (99.7% of Poisson(8) nodes).
// Phase B: groups of 4 edges; alpha/src via shfl from stash; uint4 gather
//          (8 bf16/lane). deg>16 tail recomputes inline.
// Epilogue: residual + LayerNorm (16-lane shfl) + ELU. No LDS/atomics.
// ---------------------------------------------------------------------------
__global__ __launch_bounds__(256) void k_agg(
    const unsigned* __restrict__ h, const float* __restrict__ sc,
    const int* __restrict__ row_start, const int* __restrict__ csr_src,
    const float* __restrict__ x, const float* __restrict__ gamma,
    const float* __restrict__ beta, float* __restrict__ out, int n_nodes)
{
  const int t    = threadIdx.x;
  const int lane = t & 63;
  const int g    = lane & 15;
  const int node = blockIdx.x * 16 + (t >> 6) * 4 + (lane >> 4);
  if (node >= n_nodes) return;           // uniform per 16-lane group
  const int head = g >> 2;
  const int sub  = g & 3;
  const int hh   = head * 2;
  const int beg  = row_start[node];
  const int deg  = row_start[node + 1] - beg;
  const float sdv = sc[node * 8 + hh + 1];

  // Phase A: online max/sum, stash s+src for edges sub, sub+4, sub+8, sub+12
  float m = -INFINITY, l = 0.f;
  float t0 = 0.f, t1 = 0.f, t2 = 0.f, t3 = 0.f;
  int   c0 = 0,   c1 = 0,   c2 = 0,   c3 = 0;
  if (sub < deg) {
    c0 = csr_src[beg + sub];
    float s = sc[c0 * 8 + hh] + sdv;  s = s > 0.f ? s : NEG_SLOPE * s;
    t0 = s; m = s; l = 1.f;
  }
  if (sub + 4 < deg) {
    c1 = csr_src[beg + sub + 4];
    float s = sc[c1 * 8 + hh] + sdv;  s = s > 0.f ? s : NEG_SLOPE * s;
    t1 = s;
    const float mn = fmaxf(m, s);
    l = l * __expf(m - mn) + __expf(s - mn);  m = mn;
  }
  if (sub + 8 < deg) {
    c2 = csr_src[beg + sub + 8];
    float s = sc[c2 * 8 + hh] + sdv;  s = s > 0.f ? s : NEG_SLOPE * s;
    t2 = s;
    const float mn = fmaxf(m, s);
    l = l * __expf(m - mn) + __expf(s - mn);  m = mn;
  }
  if (sub + 12 < deg) {
    c3 = csr_src[beg + sub + 12];
    float s = sc[c3 * 8 + hh] + sdv;  s = s > 0.f ? s : NEG_SLOPE * s;
    t3 = s;
    const float mn = fmaxf(m, s);
    l = l * __expf(m - mn) + __expf(s - mn);  m = mn;
  }
  for (int i = sub + 16; i < deg; i += 4) {      // rare (deg>16)
    const int cs = csr_src[beg + i];
    float s = sc[cs * 8 + hh] + sdv;  s = s > 0.f ? s : NEG_SLOPE * s;
    const float mn = fmaxf(m, s);
    l = l * __expf(m - mn) + __expf(s - mn);  m = mn;
  }
  // merge within 4-lane head group
  #pragma unroll
  for (int off = 1; off < 4; off <<= 1) {
    const float m2 = __shfl_xor(m, off);
    const float l2 = __shfl_xor(l, off);
    const float mn = fmaxf(m, m2);
    if (mn == -INFINITY) { m = -INFINITY; l = 0.f; }
    else {
      l = l * __expf(m - mn) + l2 * __expf(m2 - mn);
      m = mn;
    }
  }
  const float inv_l = (deg > 0) ? 1.f / l : 0.f;
  // alpha precompute for stashed edges (garbage where unused; never read)
  const float a0 = __expf(t0 - m) * inv_l;
  const float a1 = __expf(t1 - m) * inv_l;
  const float a2 = __expf(t2 - m) * inv_l;
  const float a3 = __expf(t3 - m) * inv_l;

  const int base3 = lane & 60;           // this lane's head-stash lane base

  // Phase B: weighted gather, groups of 4 stashed edges
  float acc[8] = {0.f, 0.f, 0.f, 0.f, 0.f, 0.f, 0.f, 0.f};
  const int deg16 = deg < 16 ? deg : 16;
  #pragma unroll
  for (int r = 0; r < 4; ++r) {
    const int i0 = r * 4;
    if (i0 >= deg16) break;              // uniform per node group
    const float ar = r == 0 ? a0 : r == 1 ? a1 : r == 2 ? a2 : a3;
    const int   cr = r == 0 ? c0 : r == 1 ? c1 : r == 2 ? c2 : c3;
    const int   n  = deg16 - i0;
    {
      const float al = __shfl(ar, base3 | 0);
      const int   sr = __shfl(cr, base3 | 0);
      const uint4 hv = *(const uint4*)(h + (size_t)sr * 64 + g * 4);
      ACC_EDGE(al, hv)
    }
    if (n > 1) {
      const float al = __shfl(ar, base3 | 1);
      const int   sr = __shfl(cr, base3 | 1);
      const uint4 hv = *(const uint4*)(h + (size_t)sr * 64 + g * 4);
      ACC_EDGE(al, hv)
    }
    if (n > 2) {
      const float al = __shfl(ar, base3 | 2);
      const int   sr = __shfl(cr, base3 | 2);
      const uint4 hv = *(const uint4*)(h + (size_t)sr * 64 + g * 4);
      ACC_EDGE(al, hv)
    }
    if (n > 3) {
      const float al = __shfl(ar, base3 | 3);
      const int   sr = __shfl(cr, base3 | 3);
      const uint4 hv = *(const uint4*)(h + (size_t)sr * 64 + g * 4);
      ACC_EDGE(al, hv)
    }
  }
  for (int i = 16; i < deg; ++i) {       // rare tail (deg>16), inline compute
    const int sr = csr_src[beg + i];
    float s = sc[sr * 8 + hh] + sdv;  s = s > 0.f ? s : NEG_SLOPE * s;
    const float al = __expf(s - m) * inv_l;
    const uint4 hv = *(const uint4*)(h + (size_t)sr * 64 + g * 4);
    ACC_EDGE(al, hv)
  }

  // residual + LayerNorm + ELU (within the 16-lane node group)
  const float4 xa = *(const float4*)(x + (size_t)node * 128 + g * 8);
  const float4 xb = *(const float4*)(x + (size_t)node * 128 + g * 8 + 4);
  float rr[8];
  rr[0] = acc[0] + xa.x;  rr[1] = acc[1] + xa.y;
  rr[2] = acc[2] + xa.z;  rr[3] = acc[3] + xa.w;
  rr[4] = acc[4] + xb.x;  rr[5] = acc[5] + xb.y;
  rr[6] = acc[6] + xb.z;  rr[7] = acc[7] + xb.w;
  float s1 = 0.f, s2 = 0.f;
  #pragma unroll
  for (int j = 0; j < 8; ++j) { s1 += rr[j]; s2 += rr[j] * rr[j]; }
  #pragma unroll
  for (int off = 1; off < 16; off <<= 1) {   // xor stays within 16-group
    s1 += __shfl_xor(s1, off);
    s2 += __shfl_xor(s2, off);
  }
  const float mu   = s1 * (1.f / 128.f);
  const float var  = s2 * (1.f / 128.f) - mu * mu;
  const float rstd = rsqrtf(var + LN_EPS);
  const float4 ga = *(const float4*)(gamma + g * 8);
  const float4 gb = *(const float4*)(gamma + g * 8 + 4);
  const float4 ba = *(const float4*)(beta  + g * 8);
  const float4 bb = *(const float4*)(beta  + g * 8 + 4);
  float4 o0, o1;
  o0.x = (rr[0] - mu) * rstd * ga.x + ba.x;
  o0.y = (rr[1] - mu) * rstd * ga.y + ba.y;
  o0.z = (rr[2] - mu) * rstd * ga.z + ba.z;
  o0.w = (rr[3] - mu) * rstd * ga.w + ba.w;
  o1.x = (rr[4] - mu) * rstd * gb.x + bb.x;
  o1.y = (rr[5] - mu) * rstd * gb.y + bb.y;
  o1.z = (rr[6] - mu) * rstd * gb.z + bb.z;
  o1.w = (rr[7] - mu) * rstd * gb.w + bb.w;
  o0.x = o0.x > 0.f ? o0.x : expm1f(o0.x);
  o0.y = o0.y > 0.f ? o0.y : expm1f(o0.y);
  o0.z = o0.z > 0.f ? o0.z : expm1f(o0.z);
  o0.w = o0.w > 0.f ? o0.w : expm1f(o0.w);
  o1.x = o1.x > 0.f ? o1.x : expm1f(o1.x);
  o1.y = o1.y > 0.f ? o1.y : expm1f(o1.y);
  o1.z = o1.z > 0.f ? o1.z : expm1f(o1.z);
  o1.w = o1.w > 0.f ? o1.w : expm1f(o1.w);
  *(float4*)(out + (size_t)node * 128 + g * 8)     = o0;
  *(float4*)(out + (size_t)node * 128 + g * 8 + 4) = o1;
}

// ---------------------------------------------------------------------------
extern "C" void kernel_launch(void* const* d_in, const int* in_sizes, int n_in,
                              void* d_out, int out_size, void* d_ws, size_t ws_size,
                              hipStream_t stream)
{
  const float* x    = (const float*)d_in[0];
  const int*   ei   = (const int*)d_in[1];
  const float* W    = (const float*)d_in[2];
  const float* a_s  = (const float*)d_in[3];
  const float* a_d  = (const float*)d_in[4];
  const float* gam  = (const float*)d_in[5];
  const float* bet  = (const float*)d_in[6];
  float* out = (float*)d_out;

  const int n_nodes = in_sizes[0] / 128;
  const int n_edges = in_sizes[1] / 2;
  const int* e_src = ei;
  const int* e_dst = ei + n_edges;

  const int nblk = (n_nodes + 1023) / 1024;    // scan blocks

  // workspace carve-up (~34 MB). counts+desc contiguous for one memset.
  char* p = (char*)d_ws;
  unsigned* h = (unsigned*)p; p += (size_t)n_nodes * 64 * sizeof(unsigned);  // bf16-packed
  float* sc   = (float*)p;  p += (size_t)n_nodes * 8 * sizeof(float);        // [ssrc|sdst] x 4 heads
  int* counts = (int*)p;    p += (size_t)((n_nodes + 1) & ~1) * sizeof(int); // 8B-align next
  unsigned long long* desc = (unsigned long long*)p; p += (size_t)nblk * sizeof(unsigned long long);
  int* row_start = (int*)p; p += (size_t)(n_nodes + 4) * sizeof(int);
  int* cursor    = (int*)p; p += (size_t)n_nodes * sizeof(int);
  int* csr_src   = (int*)p; p += (size_t)n_edges * sizeof(int);
  short* wfrag   = (short*)p; p += (size_t)2048 * 8 * sizeof(short);         // W bf16, B-frag order
  short* wafrag  = (short*)p; p += (size_t)256 * 8 * sizeof(short);          // wa bf16

  const size_t zero_bytes = (char*)(desc + nblk) - (char*)counts;
  hipMemsetAsync(counts, 0, zero_bytes, stream);

  k_prep<<<9, 256, 0, stream>>>(W, a_s, a_d, wfrag, wafrag);
  const int nproj  = (n_nodes + 127) / 128;
  const int ncount = (n_edges + 1023) / 1024;
  k_proj_count<<<nproj + ncount, 256, 0, stream>>>(
      x, wfrag, wafrag, h, sc, n_nodes, e_dst, counts, n_edges, nproj);
  k_scan<<<nblk, 256, 0, stream>>>(counts, n_nodes, n_edges, row_start, cursor, desc);
  k_fill<<<(n_edges + 255) / 256, 256, 0, stream>>>(e_src, e_dst, cursor, csr_src, n_edges);
  k_agg<<<(n_nodes + 15) / 16, 256, 0, stream>>>(h, sc, row_start, csr_src, x, gam, bet, out, n_nodes);
}